// Round 12
// baseline (397.577 us; speedup 1.0000x reference)
//
#include <hip/hip_runtime.h>

#define N_NODES 50000
#define N_EDGES 600000
#define DH 128
#define DOUT 64
#define NG 64
#define SLOPE 0.2f

using short8  = __attribute__((ext_vector_type(8))) short;
using floatx4 = __attribute__((ext_vector_type(4))) float;

__device__ __forceinline__ float leaky(float v){ return fmaxf(v, SLOPE*v); }
__device__ __forceinline__ unsigned f2bf(float x){
  unsigned u = __float_as_uint(x);
  return (u + 0x7fffu + ((u>>16)&1u)) >> 16;          // RNE bf16
}
#if __has_builtin(__builtin_amdgcn_cvt_pk_bf16_f32)
__device__ __forceinline__ unsigned pack2bf(float a, float b){
  auto t = __builtin_amdgcn_cvt_pk_bf16_f32(a, b);
  unsigned u; __builtin_memcpy(&u, &t, 4); return u;
}
#else
__device__ __forceinline__ unsigned pack2bf(float a, float b){
  return f2bf(a) | (f2bf(b) << 16);
}
#endif
__device__ __forceinline__ float bf_lo(unsigned u){ return __uint_as_float(u<<16); }
__device__ __forceinline__ float bf_hi(unsigned u){ return __uint_as_float(u & 0xffff0000u); }
__device__ __forceinline__ float rl_f(float v, int l){
  return __uint_as_float(__builtin_amdgcn_readlane(__float_as_uint(v), l));
}
__device__ __forceinline__ int rl_i(int v, int l){
  return __builtin_amdgcn_readlane(v, l);
}

// ---------------- CSR build + weight prep -----------------------------------------------
// k_hist also performs the Wt transpose+cast (fused: independent work, saves a launch).
__global__ __launch_bounds__(256)
void k_hist(const int* __restrict__ dst, int* __restrict__ counts,
            int* __restrict__ rank,
            const float* __restrict__ W1, const float* __restrict__ Wg,
            unsigned short* __restrict__ Wt){
  int gid = blockIdx.x*256 + threadIdx.x;
  if (gid < 4*16384){                          // weight prep rides along
    int mi = gid >> 14, r = gid & 16383;
    int k = r >> 7, n = r & 127;
    const float* src = (mi==0) ? W1 : (Wg + (size_t)(mi-1)*16384);
    Wt[(size_t)mi*16384 + (size_t)n*128 + k] = (unsigned short)f2bf(src[k*128 + n]);
  }
  int stride = gridDim.x*256;
  for (int e = gid; e < N_EDGES; e += stride){
    rank[e] = atomicAdd(&counts[dst[e]], 1);
  }
}

// phase 1: per-block (2048 counts) sums
__global__ __launch_bounds__(256)
void k_bscan1(const int* __restrict__ counts, int* __restrict__ bsum){
  __shared__ int sb[256];
  int base = blockIdx.x*2048;
  int t = threadIdx.x;
  int s = 0;
  #pragma unroll
  for (int j=0;j<8;j++){ int i = base + t*8 + j; if (i < N_NODES) s += counts[i]; }
  sb[t]=s; __syncthreads();
  for (int off=128; off>0; off>>=1){ if (t<off) sb[t]+=sb[t+off]; __syncthreads(); }
  if (t==0) bsum[blockIdx.x]=sb[0];
}

// phase 2+3 fused: each block redundantly prefix-sums the nb block sums (<=24 adds),
// then does its local exclusive scan + propagate.
__global__ __launch_bounds__(256)
void k_bscan3(const int* __restrict__ counts, const int* __restrict__ bsum,
              int* __restrict__ row_ptr, int nb){
  __shared__ int sb[256];
  __shared__ int sbs[64];
  int t = threadIdx.x;
  if (t < nb) sbs[t] = bsum[t];
  int base = blockIdx.x*2048;
  int c[8]; int s=0;
  #pragma unroll
  for (int j=0;j<8;j++){ int i = base+t*8+j; c[j] = (i<N_NODES)? counts[i]:0; s += c[j]; }
  sb[t]=s; __syncthreads();
  for (int off=1; off<256; off<<=1){
    int v = (t>=off)? sb[t-off] : 0;
    __syncthreads();
    sb[t]+=v;
    __syncthreads();
  }
  int boffv = 0;
  for (int b=0;b<(int)blockIdx.x;b++) boffv += sbs[b];
  int run = sb[t]-s + boffv;
  #pragma unroll
  for (int j=0;j<8;j++){
    int i = base+t*8+j;
    if (i<N_NODES){ row_ptr[i]=run; run+=c[j]; }
  }
  if ((int)blockIdx.x == nb-1 && t == 0){
    row_ptr[N_NODES] = boffv + sbs[nb-1];      // == N_EDGES
  }
}

__global__ __launch_bounds__(256)
void k_scatter(const int* __restrict__ esrc, const int* __restrict__ edst,
               const int* __restrict__ rank, const int* __restrict__ row_ptr,
               int* __restrict__ col_src){
  int stride = gridDim.x*256;
  for (int e = blockIdx.x*256 + threadIdx.x; e < N_EDGES; e += stride){
    col_src[row_ptr[edst[e]] + rank[e]] = esrc[e];
  }
}

// ---------------- MFMA GEMM (transposed D): out[node][feat] bf16, fused es/ed ----------
// 512 thr / 8 waves / 128 nodes per block. Wt: [n][k] bf16 staged in LDS (+8 pad).
// mfma(A=Wt frag, B=node frag): D[m=feature][n=node]; C/D: col(node)=lane&15,
// row(feature)=quad*4+reg -> each lane owns 4 CONSECUTIVE features per nt tile.
template<bool AFP32>
__global__ __launch_bounds__(512)
void k_linear_mfma(const void* __restrict__ Av,
                   const unsigned short* __restrict__ Wt,
                   const float* __restrict__ bias,
                   const float* __restrict__ avs, const float* __restrict__ avd,
                   unsigned short* __restrict__ outB,
                   float* __restrict__ es, float* __restrict__ ed, int nrows){
  __shared__ unsigned short wlds[128*136];
  int tid = threadIdx.x;
  #pragma unroll
  for (int i=0;i<4;i++){
    int flat = i*4096 + tid*8;
    int n = flat >> 7, kb = flat & 127;
    *(short8*)&wlds[n*136 + kb] = *(const short8*)(Wt + flat);
  }
  __syncthreads();

  int wid = tid >> 6, lane = tid & 63;
  int l15 = lane & 15, quad = lane >> 4;
  int R0 = blockIdx.x*128 + wid*16;
  int node = R0 + l15;
  int arow = node < nrows ? node : nrows-1;

  floatx4 acc[8];
  #pragma unroll
  for (int nt=0;nt<8;nt++){ acc[nt][0]=0.f; acc[nt][1]=0.f; acc[nt][2]=0.f; acc[nt][3]=0.f; }

  #pragma unroll
  for (int k0=0;k0<128;k0+=32){
    short8 a;                                   // node fragment (B operand)
    if (AFP32){
      const float* Ap = (const float*)Av + (size_t)arow*128 + quad*8 + k0;
      float4 v0 = *(const float4*)Ap;
      float4 v1 = *(const float4*)(Ap+4);
      union { short8 s; unsigned u[4]; } cv;
      cv.u[0]=pack2bf(v0.x,v0.y); cv.u[1]=pack2bf(v0.z,v0.w);
      cv.u[2]=pack2bf(v1.x,v1.y); cv.u[3]=pack2bf(v1.z,v1.w);
      a = cv.s;
    } else {
      a = *(const short8*)((const unsigned short*)Av + (size_t)arow*128 + quad*8 + k0);
    }
    const unsigned short* bp = &wlds[l15*136 + quad*8 + k0];
    #pragma unroll
    for (int nt=0;nt<8;nt++){
      short8 b = *(const short8*)(bp + nt*16*136);   // Wt fragment (A operand)
      acc[nt] = __builtin_amdgcn_mfma_f32_16x16x32_bf16(b, a, acc[nt], 0,0,0);
    }
  }

  bool nv = node < nrows;
  float ps = 0.f, pd = 0.f;
  #pragma unroll
  for (int nt=0;nt<8;nt++){
    int f0 = nt*16 + quad*4;                  // 4 consecutive features for this lane
    float4 bb = make_float4(0.f,0.f,0.f,0.f);
    if (bias) bb = *(const float4*)(bias + f0);
    float v0 = acc[nt][0]+bb.x, v1 = acc[nt][1]+bb.y;
    float v2 = acc[nt][2]+bb.z, v3 = acc[nt][3]+bb.w;
    if (es){
      float4 a4 = *(const float4*)(avs + f0);
      float4 d4 = *(const float4*)(avd + f0);
      ps = fmaf(v0,a4.x, fmaf(v1,a4.y, fmaf(v2,a4.z, fmaf(v3,a4.w, ps))));
      pd = fmaf(v0,d4.x, fmaf(v1,d4.y, fmaf(v2,d4.z, fmaf(v3,d4.w, pd))));
    }
    if (nv){
      uint2 pk; pk.x = pack2bf(v0,v1); pk.y = pack2bf(v2,v3);
      *(uint2*)(outB + (size_t)node*128 + f0) = pk;
    }
  }
  if (es){
    ps += __shfl_xor(ps, 16, 64); ps += __shfl_xor(ps, 32, 64);
    pd += __shfl_xor(pd, 16, 64); pd += __shfl_xor(pd, 32, 64);
    if (quad==0 && nv){ es[node]=ps; ed[node]=pd; }
  }
}

// ---------------- GAT aggregation: wave/node grid-stride, bf16 gather ------------------
// Self-centered softmax (w = exp(e - self_score)). Phase 1 lane-parallel w; phase 2
// readlane broadcast + coalesced gather + 2 fma, 8-deep MLP.
// LAST=true fuses global_add_pool: atomicAdd the finished (pre-rounding) h into pooled
// and skips the dead hbf store (hbf is only read for the residual in that case).
#define AGG_BLOCKS 3126
template<bool LAST>
__global__ __launch_bounds__(256)
void k_gat_agg(const unsigned* __restrict__ hp2, const float* __restrict__ es,
               const float* __restrict__ ed, const int* __restrict__ row_ptr,
               const int* __restrict__ col_src, const float* __restrict__ bg,
               unsigned* __restrict__ hbf2,
               const int* __restrict__ batch, float* __restrict__ pooled){
  int lane = threadIdx.x & 63;
  int wav0 = blockIdx.x*4 + (threadIdx.x >> 6);
  const int NW = AGG_BLOCKS*4;
  float2 bgv = *(const float2*)&bg[2*lane];

  for (int i = wav0; i < N_NODES; i += NW){
    int start = row_ptr[i], end = row_ptr[i+1];
    float edi = ed[i];
    float m0 = leaky(es[i] + edi);              // self score: softmax recentering
    unsigned us = hp2[((unsigned)i<<6) | lane];
    float acc0 = bf_lo(us), acc1 = bf_hi(us);   // self weight exp(0)=1
    float zl = (lane==0) ? 1.f : 0.f;

    for (int c0 = start; c0 < end; c0 += 64){
      int j = c0 + lane;
      bool valid = j < end;
      int s = valid ? col_src[j] : 0;
      float e = leaky(es[s] + edi);
      float w = valid ? __expf(e - m0) : 0.f;
      zl += w;
      int len = end - c0; if (len > 64) len = 64;
      int t = 0;
      for (; t + 8 <= len; t += 8){
        unsigned o0=((unsigned)rl_i(s,t  )<<6)|lane, o1=((unsigned)rl_i(s,t+1)<<6)|lane;
        unsigned o2=((unsigned)rl_i(s,t+2)<<6)|lane, o3=((unsigned)rl_i(s,t+3)<<6)|lane;
        unsigned o4=((unsigned)rl_i(s,t+4)<<6)|lane, o5=((unsigned)rl_i(s,t+5)<<6)|lane;
        unsigned o6=((unsigned)rl_i(s,t+6)<<6)|lane, o7=((unsigned)rl_i(s,t+7)<<6)|lane;
        unsigned u0=hp2[o0], u1=hp2[o1], u2=hp2[o2], u3=hp2[o3];
        unsigned u4=hp2[o4], u5=hp2[o5], u6=hp2[o6], u7=hp2[o7];
        float w0=rl_f(w,t),   w1=rl_f(w,t+1), w2=rl_f(w,t+2), w3=rl_f(w,t+3);
        float w4=rl_f(w,t+4), w5=rl_f(w,t+5), w6=rl_f(w,t+6), w7=rl_f(w,t+7);
        acc0 = fmaf(w0, bf_lo(u0), acc0); acc1 = fmaf(w0, bf_hi(u0), acc1);
        acc0 = fmaf(w1, bf_lo(u1), acc0); acc1 = fmaf(w1, bf_hi(u1), acc1);
        acc0 = fmaf(w2, bf_lo(u2), acc0); acc1 = fmaf(w2, bf_hi(u2), acc1);
        acc0 = fmaf(w3, bf_lo(u3), acc0); acc1 = fmaf(w3, bf_hi(u3), acc1);
        acc0 = fmaf(w4, bf_lo(u4), acc0); acc1 = fmaf(w4, bf_hi(u4), acc1);
        acc0 = fmaf(w5, bf_lo(u5), acc0); acc1 = fmaf(w5, bf_hi(u5), acc1);
        acc0 = fmaf(w6, bf_lo(u6), acc0); acc1 = fmaf(w6, bf_hi(u6), acc1);
        acc0 = fmaf(w7, bf_lo(u7), acc0); acc1 = fmaf(w7, bf_hi(u7), acc1);
      }
      for (; t + 4 <= len; t += 4){
        unsigned o0=((unsigned)rl_i(s,t  )<<6)|lane, o1=((unsigned)rl_i(s,t+1)<<6)|lane;
        unsigned o2=((unsigned)rl_i(s,t+2)<<6)|lane, o3=((unsigned)rl_i(s,t+3)<<6)|lane;
        unsigned u0=hp2[o0], u1=hp2[o1], u2=hp2[o2], u3=hp2[o3];
        float w0=rl_f(w,t), w1=rl_f(w,t+1), w2=rl_f(w,t+2), w3=rl_f(w,t+3);
        acc0 = fmaf(w0, bf_lo(u0), acc0); acc1 = fmaf(w0, bf_hi(u0), acc1);
        acc0 = fmaf(w1, bf_lo(u1), acc0); acc1 = fmaf(w1, bf_hi(u1), acc1);
        acc0 = fmaf(w2, bf_lo(u2), acc0); acc1 = fmaf(w2, bf_hi(u2), acc1);
        acc0 = fmaf(w3, bf_lo(u3), acc0); acc1 = fmaf(w3, bf_hi(u3), acc1);
      }
      for (; t < len; t++){
        unsigned u = hp2[((unsigned)rl_i(s,t)<<6) | lane];
        float wt = rl_f(w,t);
        acc0 = fmaf(wt, bf_lo(u), acc0);
        acc1 = fmaf(wt, bf_hi(u), acc1);
      }
    }

    float z = zl;
    #pragma unroll
    for (int off=32; off>0; off>>=1) z += __shfl_xor(z, off, 64);
    float inv = 1.f / z;
    float r0 = fmaf(acc0, inv, bgv.x);
    float r1 = fmaf(acc1, inv, bgv.y);
    r0 = r0 > 0.f ? r0 : 0.f;
    r1 = r1 > 0.f ? r1 : 0.f;
    unsigned ho = hbf2[((unsigned)i<<6) | lane];   // residual (bf16 stream)
    float hx = r0 + bf_lo(ho);
    float hy = r1 + bf_hi(ho);
    if (LAST){
      int b = batch[i];                       // fused global_add_pool
      atomicAdd(&pooled[b*128 + 2*lane],     hx);
      atomicAdd(&pooled[b*128 + 2*lane + 1], hy);
    } else {
      hbf2[((unsigned)i<<6) | lane] = pack2bf(hx, hy);
    }
  }
}

__global__ void k_final(const float* __restrict__ pooled, const float* __restrict__ W2,
                        const float* __restrict__ b2, float* __restrict__ out){
  int gid = blockIdx.x*256 + threadIdx.x;
  if (gid >= NG*DOUT) return;
  int r = gid >> 6, c = gid & 63;
  float acc = b2[c];
  #pragma unroll 4
  for (int k=0;k<DH;k++) acc = fmaf(pooled[r*DH+k], W2[k*DOUT+c], acc);
  out[(size_t)r*DOUT + c] = acc;
}

extern "C" void kernel_launch(void* const* d_in, const int* in_sizes, int n_in,
                              void* d_out, int out_size, void* d_ws, size_t ws_size,
                              hipStream_t stream){
  const float* x     = (const float*)d_in[0];
  const int*   ei    = (const int*)d_in[1];
  const int*   batch = (const int*)d_in[2];
  const float* W1    = (const float*)d_in[3];
  const float* b1    = (const float*)d_in[4];
  const float* Wg    = (const float*)d_in[5];
  const float* avs   = (const float*)d_in[6];
  const float* avd   = (const float*)d_in[7];
  const float* bgv   = (const float*)d_in[8];
  const float* W2    = (const float*)d_in[9];
  const float* b2    = (const float*)d_in[10];
  float* out = (float*)d_out;

  char* ws = (char*)d_ws;
  unsigned short* hbf = (unsigned short*)ws;       ws += (size_t)N_NODES*DH*2;   // residual stream (bf16)
  unsigned short* hp  = (unsigned short*)ws;       ws += (size_t)N_NODES*DH*2;   // GEMM out (bf16)
  float* es       = (float*)ws;                    ws += (size_t)N_NODES*4;
  float* ed       = (float*)ws;                    ws += (size_t)N_NODES*4;
  unsigned short* Wt = (unsigned short*)ws;        ws += 4*16384*2;
  int* counts     = (int*)ws;                      ws += (size_t)N_NODES*4;      // | zeroed
  float* pooled   = (float*)ws;                    ws += NG*DH*4;                // | together
  int* row_ptr    = (int*)ws;                      ws += ((size_t)N_NODES+1)*4;
  int* rank       = (int*)ws;                      ws += (size_t)N_EDGES*4;
  int* col_src    = (int*)ws;                      ws += (size_t)N_EDGES*4;
  int* bsum       = (int*)ws;                      ws += 64*4;

  const int* esrc = ei;
  const int* edst = ei + N_EDGES;

  // counts and pooled are adjacent: one memset clears both
  hipMemsetAsync(counts, 0, N_NODES*sizeof(int) + NG*DH*sizeof(float), stream);

  k_hist<<<1024, 256, 0, stream>>>(edst, counts, rank, W1, Wg, Wt);
  int nb = (N_NODES + 2047)/2048;   // 25
  k_bscan1<<<nb,256,0,stream>>>(counts, bsum);
  k_bscan3<<<nb,256,0,stream>>>(counts, bsum, row_ptr, nb);
  k_scatter<<<1024, 256, 0, stream>>>(esrc, edst, rank, row_ptr, col_src);

  int lb = (N_NODES + 127)/128;   // 391 blocks, 512 threads
  k_linear_mfma<true><<<lb, 512, 0, stream>>>(x, Wt, b1, nullptr, nullptr,
                                              hbf, nullptr, nullptr, N_NODES);
  for (int l=0; l<3; l++){
    k_linear_mfma<false><<<lb, 512, 0, stream>>>(hbf, Wt + (size_t)(l+1)*16384, nullptr,
                                                 avs + l*DH, avd + l*DH,
                                                 hp, es, ed, N_NODES);
    if (l < 2){
      k_gat_agg<false><<<AGG_BLOCKS, 256, 0, stream>>>((const unsigned*)hp, es, ed,
                                                       row_ptr, col_src, bgv + l*DH,
                                                       (unsigned*)hbf, nullptr, nullptr);
    } else {
      k_gat_agg<true><<<AGG_BLOCKS, 256, 0, stream>>>((const unsigned*)hp, es, ed,
                                                      row_ptr, col_src, bgv + l*DH,
                                                      (unsigned*)hbf, batch, pooled);
    }
  }
  k_final<<<(NG*DOUT+255)/256, 256, 0, stream>>>(pooled, W2, b2, out);
}

// Round 13
// 307.836 us; speedup vs baseline: 1.2915x; 1.2915x over previous
//
#include <hip/hip_runtime.h>

#define N_NODES 50000
#define N_EDGES 600000
#define DH 128
#define DOUT 64
#define NG 64
#define SLOPE 0.2f

using short8  = __attribute__((ext_vector_type(8))) short;
using floatx4 = __attribute__((ext_vector_type(4))) float;

__device__ __forceinline__ float leaky(float v){ return fmaxf(v, SLOPE*v); }
__device__ __forceinline__ unsigned f2bf(float x){
  unsigned u = __float_as_uint(x);
  return (u + 0x7fffu + ((u>>16)&1u)) >> 16;          // RNE bf16
}
#if __has_builtin(__builtin_amdgcn_cvt_pk_bf16_f32)
__device__ __forceinline__ unsigned pack2bf(float a, float b){
  auto t = __builtin_amdgcn_cvt_pk_bf16_f32(a, b);
  unsigned u; __builtin_memcpy(&u, &t, 4); return u;
}
#else
__device__ __forceinline__ unsigned pack2bf(float a, float b){
  return f2bf(a) | (f2bf(b) << 16);
}
#endif
__device__ __forceinline__ float bf_lo(unsigned u){ return __uint_as_float(u<<16); }
__device__ __forceinline__ float bf_hi(unsigned u){ return __uint_as_float(u & 0xffff0000u); }
__device__ __forceinline__ float rl_f(float v, int l){
  return __uint_as_float(__builtin_amdgcn_readlane(__float_as_uint(v), l));
}
__device__ __forceinline__ int rl_i(int v, int l){
  return __builtin_amdgcn_readlane(v, l);
}

// ---------------- CSR build + weight prep -----------------------------------------------
// k_hist also performs the Wt transpose+cast (fused: independent work, saves a launch).
// NOTE (R12 lesson): do NOT fuse global_add_pool into the last agg via per-lane atomics —
// 6.4M fp32 atomics over 8192 addresses is ~780-way same-address serialization (153 µs).
// k_pool's register run-accumulation over sorted batch (~100k atomics) is the right shape.
__global__ __launch_bounds__(256)
void k_hist(const int* __restrict__ dst, int* __restrict__ counts,
            int* __restrict__ rank,
            const float* __restrict__ W1, const float* __restrict__ Wg,
            unsigned short* __restrict__ Wt){
  int gid = blockIdx.x*256 + threadIdx.x;
  if (gid < 4*16384){                          // weight prep rides along
    int mi = gid >> 14, r = gid & 16383;
    int k = r >> 7, n = r & 127;
    const float* src = (mi==0) ? W1 : (Wg + (size_t)(mi-1)*16384);
    Wt[(size_t)mi*16384 + (size_t)n*128 + k] = (unsigned short)f2bf(src[k*128 + n]);
  }
  int stride = gridDim.x*256;
  for (int e = gid; e < N_EDGES; e += stride){
    rank[e] = atomicAdd(&counts[dst[e]], 1);
  }
}

// phase 1: per-block (2048 counts) sums
__global__ __launch_bounds__(256)
void k_bscan1(const int* __restrict__ counts, int* __restrict__ bsum){
  __shared__ int sb[256];
  int base = blockIdx.x*2048;
  int t = threadIdx.x;
  int s = 0;
  #pragma unroll
  for (int j=0;j<8;j++){ int i = base + t*8 + j; if (i < N_NODES) s += counts[i]; }
  sb[t]=s; __syncthreads();
  for (int off=128; off>0; off>>=1){ if (t<off) sb[t]+=sb[t+off]; __syncthreads(); }
  if (t==0) bsum[blockIdx.x]=sb[0];
}

// phase 2+3 fused: each block redundantly prefix-sums the nb block sums (<=24 adds),
// then does its local exclusive scan + propagate.
__global__ __launch_bounds__(256)
void k_bscan3(const int* __restrict__ counts, const int* __restrict__ bsum,
              int* __restrict__ row_ptr, int nb){
  __shared__ int sb[256];
  __shared__ int sbs[64];
  int t = threadIdx.x;
  if (t < nb) sbs[t] = bsum[t];
  int base = blockIdx.x*2048;
  int c[8]; int s=0;
  #pragma unroll
  for (int j=0;j<8;j++){ int i = base+t*8+j; c[j] = (i<N_NODES)? counts[i]:0; s += c[j]; }
  sb[t]=s; __syncthreads();
  for (int off=1; off<256; off<<=1){
    int v = (t>=off)? sb[t-off] : 0;
    __syncthreads();
    sb[t]+=v;
    __syncthreads();
  }
  int boffv = 0;
  for (int b=0;b<(int)blockIdx.x;b++) boffv += sbs[b];
  int run = sb[t]-s + boffv;
  #pragma unroll
  for (int j=0;j<8;j++){
    int i = base+t*8+j;
    if (i<N_NODES){ row_ptr[i]=run; run+=c[j]; }
  }
  if ((int)blockIdx.x == nb-1 && t == 0){
    row_ptr[N_NODES] = boffv + sbs[nb-1];      // == N_EDGES
  }
}

__global__ __launch_bounds__(256)
void k_scatter(const int* __restrict__ esrc, const int* __restrict__ edst,
               const int* __restrict__ rank, const int* __restrict__ row_ptr,
               int* __restrict__ col_src){
  int stride = gridDim.x*256;
  for (int e = blockIdx.x*256 + threadIdx.x; e < N_EDGES; e += stride){
    col_src[row_ptr[edst[e]] + rank[e]] = esrc[e];
  }
}

// ---------------- MFMA GEMM (transposed D): out[node][feat] bf16, fused es/ed ----------
// 512 thr / 8 waves / 128 nodes per block. Wt: [n][k] bf16 staged in LDS (+8 pad).
// mfma(A=Wt frag, B=node frag): D[m=feature][n=node]; C/D: col(node)=lane&15,
// row(feature)=quad*4+reg -> each lane owns 4 CONSECUTIVE features per nt tile.
template<bool AFP32>
__global__ __launch_bounds__(512)
void k_linear_mfma(const void* __restrict__ Av,
                   const unsigned short* __restrict__ Wt,
                   const float* __restrict__ bias,
                   const float* __restrict__ avs, const float* __restrict__ avd,
                   unsigned short* __restrict__ outB,
                   float* __restrict__ es, float* __restrict__ ed, int nrows){
  __shared__ unsigned short wlds[128*136];
  int tid = threadIdx.x;
  #pragma unroll
  for (int i=0;i<4;i++){
    int flat = i*4096 + tid*8;
    int n = flat >> 7, kb = flat & 127;
    *(short8*)&wlds[n*136 + kb] = *(const short8*)(Wt + flat);
  }
  __syncthreads();

  int wid = tid >> 6, lane = tid & 63;
  int l15 = lane & 15, quad = lane >> 4;
  int R0 = blockIdx.x*128 + wid*16;
  int node = R0 + l15;
  int arow = node < nrows ? node : nrows-1;

  floatx4 acc[8];
  #pragma unroll
  for (int nt=0;nt<8;nt++){ acc[nt][0]=0.f; acc[nt][1]=0.f; acc[nt][2]=0.f; acc[nt][3]=0.f; }

  #pragma unroll
  for (int k0=0;k0<128;k0+=32){
    short8 a;                                   // node fragment (B operand)
    if (AFP32){
      const float* Ap = (const float*)Av + (size_t)arow*128 + quad*8 + k0;
      float4 v0 = *(const float4*)Ap;
      float4 v1 = *(const float4*)(Ap+4);
      union { short8 s; unsigned u[4]; } cv;
      cv.u[0]=pack2bf(v0.x,v0.y); cv.u[1]=pack2bf(v0.z,v0.w);
      cv.u[2]=pack2bf(v1.x,v1.y); cv.u[3]=pack2bf(v1.z,v1.w);
      a = cv.s;
    } else {
      a = *(const short8*)((const unsigned short*)Av + (size_t)arow*128 + quad*8 + k0);
    }
    const unsigned short* bp = &wlds[l15*136 + quad*8 + k0];
    #pragma unroll
    for (int nt=0;nt<8;nt++){
      short8 b = *(const short8*)(bp + nt*16*136);   // Wt fragment (A operand)
      acc[nt] = __builtin_amdgcn_mfma_f32_16x16x32_bf16(b, a, acc[nt], 0,0,0);
    }
  }

  bool nv = node < nrows;
  float ps = 0.f, pd = 0.f;
  #pragma unroll
  for (int nt=0;nt<8;nt++){
    int f0 = nt*16 + quad*4;                  // 4 consecutive features for this lane
    float4 bb = make_float4(0.f,0.f,0.f,0.f);
    if (bias) bb = *(const float4*)(bias + f0);
    float v0 = acc[nt][0]+bb.x, v1 = acc[nt][1]+bb.y;
    float v2 = acc[nt][2]+bb.z, v3 = acc[nt][3]+bb.w;
    if (es){
      float4 a4 = *(const float4*)(avs + f0);
      float4 d4 = *(const float4*)(avd + f0);
      ps = fmaf(v0,a4.x, fmaf(v1,a4.y, fmaf(v2,a4.z, fmaf(v3,a4.w, ps))));
      pd = fmaf(v0,d4.x, fmaf(v1,d4.y, fmaf(v2,d4.z, fmaf(v3,d4.w, pd))));
    }
    if (nv){
      uint2 pk; pk.x = pack2bf(v0,v1); pk.y = pack2bf(v2,v3);
      *(uint2*)(outB + (size_t)node*128 + f0) = pk;
    }
  }
  if (es){
    ps += __shfl_xor(ps, 16, 64); ps += __shfl_xor(ps, 32, 64);
    pd += __shfl_xor(pd, 16, 64); pd += __shfl_xor(pd, 32, 64);
    if (quad==0 && nv){ es[node]=ps; ed[node]=pd; }
  }
}

// ---------------- GAT aggregation: wave/node grid-stride, bf16 gather ------------------
// Self-centered softmax (w = exp(e - self_score)). Phase 1 lane-parallel w; phase 2
// readlane broadcast + coalesced gather (32-bit packed offsets) + 2 fma, 8-deep MLP.
#define AGG_BLOCKS 3126
__global__ __launch_bounds__(256)
void k_gat_agg(const unsigned* __restrict__ hp2, const float* __restrict__ es,
               const float* __restrict__ ed, const int* __restrict__ row_ptr,
               const int* __restrict__ col_src, const float* __restrict__ bg,
               unsigned* __restrict__ hbf2){
  int lane = threadIdx.x & 63;
  int wav0 = blockIdx.x*4 + (threadIdx.x >> 6);
  const int NW = AGG_BLOCKS*4;
  float2 bgv = *(const float2*)&bg[2*lane];

  for (int i = wav0; i < N_NODES; i += NW){
    int start = row_ptr[i], end = row_ptr[i+1];
    float edi = ed[i];
    float m0 = leaky(es[i] + edi);              // self score: softmax recentering
    unsigned us = hp2[((unsigned)i<<6) | lane];
    float acc0 = bf_lo(us), acc1 = bf_hi(us);   // self weight exp(0)=1
    float zl = (lane==0) ? 1.f : 0.f;

    for (int c0 = start; c0 < end; c0 += 64){
      int j = c0 + lane;
      bool valid = j < end;
      int s = valid ? col_src[j] : 0;
      float e = leaky(es[s] + edi);
      float w = valid ? __expf(e - m0) : 0.f;
      zl += w;
      int len = end - c0; if (len > 64) len = 64;
      int t = 0;
      for (; t + 8 <= len; t += 8){
        unsigned o0=((unsigned)rl_i(s,t  )<<6)|lane, o1=((unsigned)rl_i(s,t+1)<<6)|lane;
        unsigned o2=((unsigned)rl_i(s,t+2)<<6)|lane, o3=((unsigned)rl_i(s,t+3)<<6)|lane;
        unsigned o4=((unsigned)rl_i(s,t+4)<<6)|lane, o5=((unsigned)rl_i(s,t+5)<<6)|lane;
        unsigned o6=((unsigned)rl_i(s,t+6)<<6)|lane, o7=((unsigned)rl_i(s,t+7)<<6)|lane;
        unsigned u0=hp2[o0], u1=hp2[o1], u2=hp2[o2], u3=hp2[o3];
        unsigned u4=hp2[o4], u5=hp2[o5], u6=hp2[o6], u7=hp2[o7];
        float w0=rl_f(w,t),   w1=rl_f(w,t+1), w2=rl_f(w,t+2), w3=rl_f(w,t+3);
        float w4=rl_f(w,t+4), w5=rl_f(w,t+5), w6=rl_f(w,t+6), w7=rl_f(w,t+7);
        acc0 = fmaf(w0, bf_lo(u0), acc0); acc1 = fmaf(w0, bf_hi(u0), acc1);
        acc0 = fmaf(w1, bf_lo(u1), acc0); acc1 = fmaf(w1, bf_hi(u1), acc1);
        acc0 = fmaf(w2, bf_lo(u2), acc0); acc1 = fmaf(w2, bf_hi(u2), acc1);
        acc0 = fmaf(w3, bf_lo(u3), acc0); acc1 = fmaf(w3, bf_hi(u3), acc1);
        acc0 = fmaf(w4, bf_lo(u4), acc0); acc1 = fmaf(w4, bf_hi(u4), acc1);
        acc0 = fmaf(w5, bf_lo(u5), acc0); acc1 = fmaf(w5, bf_hi(u5), acc1);
        acc0 = fmaf(w6, bf_lo(u6), acc0); acc1 = fmaf(w6, bf_hi(u6), acc1);
        acc0 = fmaf(w7, bf_lo(u7), acc0); acc1 = fmaf(w7, bf_hi(u7), acc1);
      }
      for (; t + 4 <= len; t += 4){
        unsigned o0=((unsigned)rl_i(s,t  )<<6)|lane, o1=((unsigned)rl_i(s,t+1)<<6)|lane;
        unsigned o2=((unsigned)rl_i(s,t+2)<<6)|lane, o3=((unsigned)rl_i(s,t+3)<<6)|lane;
        unsigned u0=hp2[o0], u1=hp2[o1], u2=hp2[o2], u3=hp2[o3];
        float w0=rl_f(w,t), w1=rl_f(w,t+1), w2=rl_f(w,t+2), w3=rl_f(w,t+3);
        acc0 = fmaf(w0, bf_lo(u0), acc0); acc1 = fmaf(w0, bf_hi(u0), acc1);
        acc0 = fmaf(w1, bf_lo(u1), acc0); acc1 = fmaf(w1, bf_hi(u1), acc1);
        acc0 = fmaf(w2, bf_lo(u2), acc0); acc1 = fmaf(w2, bf_hi(u2), acc1);
        acc0 = fmaf(w3, bf_lo(u3), acc0); acc1 = fmaf(w3, bf_hi(u3), acc1);
      }
      for (; t < len; t++){
        unsigned u = hp2[((unsigned)rl_i(s,t)<<6) | lane];
        float wt = rl_f(w,t);
        acc0 = fmaf(wt, bf_lo(u), acc0);
        acc1 = fmaf(wt, bf_hi(u), acc1);
      }
    }

    float z = zl;
    #pragma unroll
    for (int off=32; off>0; off>>=1) z += __shfl_xor(z, off, 64);
    float inv = 1.f / z;
    float r0 = fmaf(acc0, inv, bgv.x);
    float r1 = fmaf(acc1, inv, bgv.y);
    r0 = r0 > 0.f ? r0 : 0.f;
    r1 = r1 > 0.f ? r1 : 0.f;
    unsigned ho = hbf2[((unsigned)i<<6) | lane];   // residual (bf16 stream)
    hbf2[((unsigned)i<<6) | lane] = pack2bf(r0 + bf_lo(ho), r1 + bf_hi(ho));
  }
}

// ---------------- global_add_pool (batch sorted -> run accumulate), bf16 in ------------
__global__ __launch_bounds__(256)
void k_pool(const unsigned* __restrict__ hbf2, const int* __restrict__ batch,
            float* __restrict__ pooled){
  int lane = threadIdx.x & 63, w = threadIdx.x >> 6;
  int n0 = blockIdx.x*128 + w*32;
  if (n0 >= N_NODES) return;
  int nEnd = n0 + 32; if (nEnd > N_NODES) nEnd = N_NODES;
  int cur = batch[n0];
  float a0 = 0.f, a1 = 0.f;
  for (int n = n0; n < nEnd; n++){
    int b = batch[n];
    if (b != cur){
      atomicAdd(&pooled[cur*128 + 2*lane],     a0);
      atomicAdd(&pooled[cur*128 + 2*lane + 1], a1);
      a0 = 0.f; a1 = 0.f; cur = b;
    }
    unsigned u = hbf2[((unsigned)n<<6) | lane];
    a0 += bf_lo(u); a1 += bf_hi(u);
  }
  atomicAdd(&pooled[cur*128 + 2*lane],     a0);
  atomicAdd(&pooled[cur*128 + 2*lane + 1], a1);
}

__global__ void k_final(const float* __restrict__ pooled, const float* __restrict__ W2,
                        const float* __restrict__ b2, float* __restrict__ out){
  int gid = blockIdx.x*256 + threadIdx.x;
  if (gid >= NG*DOUT) return;
  int r = gid >> 6, c = gid & 63;
  float acc = b2[c];
  #pragma unroll 4
  for (int k=0;k<DH;k++) acc = fmaf(pooled[r*DH+k], W2[k*DOUT+c], acc);
  out[(size_t)r*DOUT + c] = acc;
}

extern "C" void kernel_launch(void* const* d_in, const int* in_sizes, int n_in,
                              void* d_out, int out_size, void* d_ws, size_t ws_size,
                              hipStream_t stream){
  const float* x     = (const float*)d_in[0];
  const int*   ei    = (const int*)d_in[1];
  const int*   batch = (const int*)d_in[2];
  const float* W1    = (const float*)d_in[3];
  const float* b1    = (const float*)d_in[4];
  const float* Wg    = (const float*)d_in[5];
  const float* avs   = (const float*)d_in[6];
  const float* avd   = (const float*)d_in[7];
  const float* bgv   = (const float*)d_in[8];
  const float* W2    = (const float*)d_in[9];
  const float* b2    = (const float*)d_in[10];
  float* out = (float*)d_out;

  char* ws = (char*)d_ws;
  unsigned short* hbf = (unsigned short*)ws;       ws += (size_t)N_NODES*DH*2;   // residual stream (bf16)
  unsigned short* hp  = (unsigned short*)ws;       ws += (size_t)N_NODES*DH*2;   // GEMM out (bf16)
  float* es       = (float*)ws;                    ws += (size_t)N_NODES*4;
  float* ed       = (float*)ws;                    ws += (size_t)N_NODES*4;
  float* pooled   = (float*)ws;                    ws += NG*DH*4;
  unsigned short* Wt = (unsigned short*)ws;        ws += 4*16384*2;
  int* counts     = (int*)ws;                      ws += (size_t)N_NODES*4;
  int* row_ptr    = (int*)ws;                      ws += ((size_t)N_NODES+1)*4;
  int* rank       = (int*)ws;                      ws += (size_t)N_EDGES*4;
  int* col_src    = (int*)ws;                      ws += (size_t)N_EDGES*4;
  int* bsum       = (int*)ws;                      ws += 64*4;

  const int* esrc = ei;
  const int* edst = ei + N_EDGES;

  hipMemsetAsync(counts, 0, N_NODES*sizeof(int), stream);
  hipMemsetAsync(pooled, 0, NG*DH*sizeof(float), stream);

  k_hist<<<1024, 256, 0, stream>>>(edst, counts, rank, W1, Wg, Wt);
  int nb = (N_NODES + 2047)/2048;   // 25
  k_bscan1<<<nb,256,0,stream>>>(counts, bsum);
  k_bscan3<<<nb,256,0,stream>>>(counts, bsum, row_ptr, nb);
  k_scatter<<<1024, 256, 0, stream>>>(esrc, edst, rank, row_ptr, col_src);

  int lb = (N_NODES + 127)/128;   // 391 blocks, 512 threads
  k_linear_mfma<true><<<lb, 512, 0, stream>>>(x, Wt, b1, nullptr, nullptr,
                                              hbf, nullptr, nullptr, N_NODES);
  for (int l=0; l<3; l++){
    k_linear_mfma<false><<<lb, 512, 0, stream>>>(hbf, Wt + (size_t)(l+1)*16384, nullptr,
                                                 avs + l*DH, avd + l*DH,
                                                 hp, es, ed, N_NODES);
    k_gat_agg<<<AGG_BLOCKS, 256, 0, stream>>>((const unsigned*)hp, es, ed,
                                              row_ptr, col_src, bgv + l*DH,
                                              (unsigned*)hbf);
  }
  k_pool<<<(N_NODES+127)/128, 256, 0, stream>>>((const unsigned*)hbf, batch, pooled);
  k_final<<<(NG*DOUT+255)/256, 256, 0, stream>>>(pooled, W2, b2, out);
}